// Round 1
// baseline (19.318 us; speedup 1.0000x reference)
//
#include <hip/hip_runtime.h>
#include <math.h>

// Fused quanvolution + linear + log_softmax.
// One block per batch element. Phase 1: 196 threads compute the 196 patches'
// 4 Z-expectations into LDS. Phase 2: all 256 threads do the 784x10 matvec,
// wave-reduce, thread 0 finishes log_softmax.
//
// Circuit factorization (verified by hand):
//   wires(0,1): RX(t0)@0, RY(t1)@1, CNOT(0,1), RY(t4)@0    -> simulate 4 complex amps
//   wires(2,3): RZ(t2)@2, RX(t3)@3, CNOT(2,3), RZ(t5)@3    -> RZs are phase-only
//       => e2 = cos(p2);  e3 = cos(t3)*cos(p2)*cos(p3)
__global__ __launch_bounds__(256) void quanv_fused_kernel(
    const float* __restrict__ x,      // [B,28,28]
    const float* __restrict__ theta,  // [6]
    const float* __restrict__ W,      // [10,784]
    const float* __restrict__ bias,   // [10]
    float* __restrict__ out)          // [B,10] log-probs
{
    __shared__ float feats[784];
    __shared__ float red[4][10];

    const int b   = blockIdx.x;
    const int tid = threadIdx.x;

    // -------- Phase 1: quantum patch features --------
    if (tid < 196) {
        // theta-derived constants (broadcast loads, cheap trig)
        float sx0, cx0, sy1, cy1, sy4, cy4;
        __sincosf(0.5f * theta[0], &sx0, &cx0);   // RX wire0
        __sincosf(0.5f * theta[1], &sy1, &cy1);   // RY wire1
        __sincosf(0.5f * theta[4], &sy4, &cy4);   // RY wire0
        const float cth3 = __cosf(theta[3]);      // cos(theta3) for e3

        const int r = tid / 14, c = tid % 14;
        const float* px = x + (size_t)b * 784 + (2 * r) * 28 + 2 * c;
        const float p0 = px[0];
        const float p1 = px[1];
        const float p2 = px[28];
        const float p3 = px[29];

        float s0, c0, s1, c1, s2, c2, s3, c3;
        __sincosf(0.5f * p0, &s0, &c0);
        __sincosf(0.5f * p1, &s1, &c1);
        __sincosf(0.5f * p2, &s2, &c2);
        __sincosf(0.5f * p3, &s3, &c3);

        // ---- pair (0,1): basis |ij>, idx = i*2+j ----
        const float v0 = c0 * c1, v1 = c0 * s1, v2 = s0 * c1, v3 = s0 * s1;
        // RX(t0) on wire0: pairs (0,2),(1,3); inputs real
        const float Ar0 =  cx0 * v0, Ai0 = -sx0 * v2;
        const float Ar1 =  cx0 * v1, Ai1 = -sx0 * v3;
        const float Ar2 =  cx0 * v2, Ai2 = -sx0 * v0;
        const float Ar3 =  cx0 * v3, Ai3 = -sx0 * v1;
        // RY(t1) on wire1: pairs (0,1),(2,3); real matrix
        const float Br0 = cy1 * Ar0 - sy1 * Ar1, Bi0 = cy1 * Ai0 - sy1 * Ai1;
        const float Br1 = sy1 * Ar0 + cy1 * Ar1, Bi1 = sy1 * Ai0 + cy1 * Ai1;
        const float Br2 = cy1 * Ar2 - sy1 * Ar3, Bi2 = cy1 * Ai2 - sy1 * Ai3;
        const float Br3 = sy1 * Ar2 + cy1 * Ar3, Bi3 = sy1 * Ai2 + cy1 * Ai3;
        // CNOT(0,1): swap idx 2 and 3. C = [B0, B1, B3, B2]
        const float Cr2 = Br3, Ci2 = Bi3;
        const float Cr3 = Br2, Ci3 = Bi2;
        // RY(t4) on wire0: pairs (0,2),(1,3)
        const float Dr0 = cy4 * Br0 - sy4 * Cr2, Di0 = cy4 * Bi0 - sy4 * Ci2;
        const float Dr2 = sy4 * Br0 + cy4 * Cr2, Di2 = sy4 * Bi0 + cy4 * Ci2;
        const float Dr1 = cy4 * Br1 - sy4 * Cr3, Di1 = cy4 * Bi1 - sy4 * Ci3;
        const float Dr3 = sy4 * Br1 + cy4 * Cr3, Di3 = sy4 * Bi1 + cy4 * Ci3;

        const float q0 = Dr0 * Dr0 + Di0 * Di0;
        const float q1 = Dr1 * Dr1 + Di1 * Di1;
        const float q2 = Dr2 * Dr2 + Di2 * Di2;
        const float q3 = Dr3 * Dr3 + Di3 * Di3;
        const float e0 = q0 + q1 - q2 - q3;   // <Z> wire0 (high bit)
        const float e1 = q0 - q1 + q2 - q3;   // <Z> wire1 (low bit)

        // ---- pair (2,3): analytic ----
        const float cp2 = c2 * c2 - s2 * s2;  // cos(p2)
        const float cp3 = c3 * c3 - s3 * s3;  // cos(p3)
        const float e2 = cp2;
        const float e3 = cth3 * cp2 * cp3;

        feats[tid * 4 + 0] = e0;
        feats[tid * 4 + 1] = e1;
        feats[tid * 4 + 2] = e2;
        feats[tid * 4 + 3] = e3;
    }
    __syncthreads();

    // -------- Phase 2: 784 -> 10 matvec + log_softmax --------
    float acc[10];
#pragma unroll
    for (int k = 0; k < 10; ++k) acc[k] = 0.f;

    for (int i = tid; i < 784; i += 256) {
        const float f = feats[i];
#pragma unroll
        for (int k = 0; k < 10; ++k) acc[k] += f * W[k * 784 + i];
    }

    // wave64 shuffle reduction
#pragma unroll
    for (int off = 32; off > 0; off >>= 1) {
#pragma unroll
        for (int k = 0; k < 10; ++k) acc[k] += __shfl_down(acc[k], off, 64);
    }
    const int wave = tid >> 6;
    if ((tid & 63) == 0) {
#pragma unroll
        for (int k = 0; k < 10; ++k) red[wave][k] = acc[k];
    }
    __syncthreads();

    if (tid == 0) {
        float logit[10];
        float m = -1e30f;
#pragma unroll
        for (int k = 0; k < 10; ++k) {
            const float v = red[0][k] + red[1][k] + red[2][k] + red[3][k] + bias[k];
            logit[k] = v;
            m = fmaxf(m, v);
        }
        float s = 0.f;
#pragma unroll
        for (int k = 0; k < 10; ++k) s += __expf(logit[k] - m);
        const float lse = m + __logf(s);
#pragma unroll
        for (int k = 0; k < 10; ++k) out[(size_t)b * 10 + k] = logit[k] - lse;
    }
}

extern "C" void kernel_launch(void* const* d_in, const int* in_sizes, int n_in,
                              void* d_out, int out_size, void* d_ws, size_t ws_size,
                              hipStream_t stream) {
    const float* x     = (const float*)d_in[0];  // [B,28,28]
    const float* theta = (const float*)d_in[1];  // [6]
    const float* W     = (const float*)d_in[2];  // [10,784]
    const float* bias  = (const float*)d_in[3];  // [10]
    float* out = (float*)d_out;                  // [B,10]

    const int B = in_sizes[0] / 784;
    quanv_fused_kernel<<<dim3(B), dim3(256), 0, stream>>>(x, theta, W, bias, out);
}

// Round 2
// 13.926 us; speedup vs baseline: 1.3872x; 1.3872x over previous
//
#include <hip/hip_runtime.h>
#include <math.h>

// Fused quanvolution + linear + log_softmax, barrier-free.
// wave <-> sample: each 64-lane wave computes one batch element end-to-end.
//   - per patch p (lane-strided over 196): 6 transcendentals + ~60 VALU give
//     the 4 Z-expectations e0..e3, which are immediately FMA'd into acc[10]
//     via one coalesced float4 load of W[k][4p..4p+3] per class.
//   - one 6-step __shfl_xor butterfly per sample (60 shuffles), lane 0 does
//     the 10-way log_softmax and writes out.
//
// Circuit factorization (verified round 1, absmax 1.6e-2 vs 7.1e-2 thr):
//   wires(0,1): RX(t0)@0, RY(t1)@1, CNOT(0,1), RY(t4)@0 -> 4 complex amps
//   wires(2,3): RZs are phase-only => e2 = cos(p2); e3 = cos(t3)cos(p2)cos(p3)
__global__ __launch_bounds__(256) void quanv_fused_kernel(
    const float* __restrict__ x,      // [B,28,28]
    const float* __restrict__ theta,  // [6]
    const float* __restrict__ W,      // [10,784]
    const float* __restrict__ bias,   // [10]
    float* __restrict__ out,          // [B,10] log-probs
    int B)
{
    const int wave = threadIdx.x >> 6;
    const int lane = threadIdx.x & 63;
    const int b    = blockIdx.x * 4 + wave;
    if (b >= B) return;

    // theta-derived constants (loop-invariant, broadcast loads)
    float sx0, cx0, sy1, cy1, sy4, cy4;
    __sincosf(0.5f * theta[0], &sx0, &cx0);   // RX wire0
    __sincosf(0.5f * theta[1], &sy1, &cy1);   // RY wire1
    __sincosf(0.5f * theta[4], &sy4, &cy4);   // RY wire0
    const float cth3 = __cosf(theta[3]);      // cos(theta3) for e3

    const float* __restrict__ xb = x + (size_t)b * 784;

    float acc[10];
#pragma unroll
    for (int k = 0; k < 10; ++k) acc[k] = 0.f;

    for (int p = lane; p < 196; p += 64) {
        const int r = p / 14, c = p - r * 14;
        const float* px = xb + r * 56 + c * 2;
        const float p0 = px[0];
        const float p1 = px[1];
        const float p2 = px[28];
        const float p3 = px[29];

        // half-angle sincos only where the complex amps need it
        float s0, c0, s1, c1;
        __sincosf(0.5f * p0, &s0, &c0);
        __sincosf(0.5f * p1, &s1, &c1);
        const float cp2 = __cosf(p2);
        const float cp3 = __cosf(p3);

        // ---- pair (0,1): basis |ij>, idx = i*2+j ----
        const float v0 = c0 * c1, v1 = c0 * s1, v2 = s0 * c1, v3 = s0 * s1;
        // RX(t0) on wire0
        const float Ar0 =  cx0 * v0, Ai0 = -sx0 * v2;
        const float Ar1 =  cx0 * v1, Ai1 = -sx0 * v3;
        const float Ar2 =  cx0 * v2, Ai2 = -sx0 * v0;
        const float Ar3 =  cx0 * v3, Ai3 = -sx0 * v1;
        // RY(t1) on wire1
        const float Br0 = cy1 * Ar0 - sy1 * Ar1, Bi0 = cy1 * Ai0 - sy1 * Ai1;
        const float Br1 = sy1 * Ar0 + cy1 * Ar1, Bi1 = sy1 * Ai0 + cy1 * Ai1;
        const float Br2 = cy1 * Ar2 - sy1 * Ar3, Bi2 = cy1 * Ai2 - sy1 * Ai3;
        const float Br3 = sy1 * Ar2 + cy1 * Ar3, Bi3 = sy1 * Ai2 + cy1 * Ai3;
        // CNOT(0,1): swap idx 2,3 ; then RY(t4) on wire0 (pairs (0,2),(1,3))
        const float Cr2 = Br3, Ci2 = Bi3;
        const float Cr3 = Br2, Ci3 = Bi2;
        const float Dr0 = cy4 * Br0 - sy4 * Cr2, Di0 = cy4 * Bi0 - sy4 * Ci2;
        const float Dr2 = sy4 * Br0 + cy4 * Cr2, Di2 = sy4 * Bi0 + cy4 * Ci2;
        const float Dr1 = cy4 * Br1 - sy4 * Cr3, Di1 = cy4 * Bi1 - sy4 * Ci3;
        const float Dr3 = sy4 * Br1 + cy4 * Cr3, Di3 = sy4 * Bi1 + cy4 * Ci3;

        const float q0 = Dr0 * Dr0 + Di0 * Di0;
        const float q1 = Dr1 * Dr1 + Di1 * Di1;
        const float q2 = Dr2 * Dr2 + Di2 * Di2;
        const float q3 = Dr3 * Dr3 + Di3 * Di3;
        const float e0 = q0 + q1 - q2 - q3;   // <Z> wire0
        const float e1 = q0 - q1 + q2 - q3;   // <Z> wire1
        const float e2 = cp2;                 // <Z> wire2
        const float e3 = cth3 * cp2 * cp3;    // <Z> wire3

        // fuse straight into the linear layer: one float4 of W per class
#pragma unroll
        for (int k = 0; k < 10; ++k) {
            const float4 w4 = *reinterpret_cast<const float4*>(&W[k * 784 + 4 * p]);
            acc[k] += e0 * w4.x + e1 * w4.y + e2 * w4.z + e3 * w4.w;
        }
    }

    // in-wave butterfly reduction (all lanes converged here)
#pragma unroll
    for (int m = 1; m < 64; m <<= 1) {
#pragma unroll
        for (int k = 0; k < 10; ++k) acc[k] += __shfl_xor(acc[k], m, 64);
    }

    if (lane == 0) {
        float logit[10];
        float mx = -1e30f;
#pragma unroll
        for (int k = 0; k < 10; ++k) {
            const float v = acc[k] + bias[k];
            logit[k] = v;
            mx = fmaxf(mx, v);
        }
        float s = 0.f;
#pragma unroll
        for (int k = 0; k < 10; ++k) s += __expf(logit[k] - mx);
        const float lse = mx + __logf(s);
#pragma unroll
        for (int k = 0; k < 10; ++k) out[(size_t)b * 10 + k] = logit[k] - lse;
    }
}

extern "C" void kernel_launch(void* const* d_in, const int* in_sizes, int n_in,
                              void* d_out, int out_size, void* d_ws, size_t ws_size,
                              hipStream_t stream) {
    const float* x     = (const float*)d_in[0];  // [B,28,28]
    const float* theta = (const float*)d_in[1];  // [6]
    const float* W     = (const float*)d_in[2];  // [10,784]
    const float* bias  = (const float*)d_in[3];  // [10]
    float* out = (float*)d_out;                  // [B,10]

    const int B = in_sizes[0] / 784;             // 4096
    const int blocks = (B + 3) / 4;              // 4 samples (waves) per block
    quanv_fused_kernel<<<dim3(blocks), dim3(256), 0, stream>>>(x, theta, W, bias, out, B);
}

// Round 3
// 13.267 us; speedup vs baseline: 1.4561x; 1.0497x over previous
//
#include <hip/hip_runtime.h>
#include <math.h>

// Fused quanvolution + linear + log_softmax, closed-form circuit.
//
// The 4-qubit circuit factorizes into pairs (0,1) and (2,3); working the
// algebra all the way through (verified against the numerically-passing
// round-1 amplitude simulation):
//   e0 = cos(t0)cos(t4)*cos(p0) - sin(t4)*sin(p0)*sin(p1+t1)
//   e1 = cos(t0)*cos(p0)*cos(p1+t1)
//   e2 = cos(p2)
//   e3 = cos(t3)*cos(p2)*cos(p3)
// where (p0,p1,p2,p3) are the 2x2 patch pixels. RZ(t2), RZ(t5) are
// phase-only => drop out of all Z-expectations.
//
// wave <-> sample: each 64-lane wave computes one batch element end-to-end:
// 3 uniform patch iterations + 4-lane tail (196 = 3*64 + 4), features FMA'd
// straight into acc[10] via coalesced float4 W loads, 6-step butterfly
// reduction, lane-parallel log_softmax epilogue with a coalesced 40B store.
__global__ __launch_bounds__(256) void quanv_fused_kernel(
    const float* __restrict__ x,      // [B,28,28]
    const float* __restrict__ theta,  // [6]
    const float* __restrict__ W,      // [10,784]
    const float* __restrict__ bias,   // [10]
    float* __restrict__ out,          // [B,10] log-probs
    int B)
{
    const int wave = threadIdx.x >> 6;
    const int lane = threadIdx.x & 63;
    const int b    = blockIdx.x * 4 + wave;
    if (b >= B) return;

    // theta-derived constants (loop-invariant broadcast)
    const float t1 = theta[1];
    const float K1 = __cosf(theta[0]) * __cosf(theta[4]);  // cos t0 cos t4
    const float K2 = __sinf(theta[4]);                     // sin t4
    const float K3 = __cosf(theta[0]);                     // cos t0
    const float K4 = __cosf(theta[3]);                     // cos t3

    const float* __restrict__ xb = x + (size_t)b * 784;

    float acc[10];
#pragma unroll
    for (int k = 0; k < 10; ++k) acc[k] = 0.f;

    auto do_patch = [&](int p) {
        const int r = p / 14, c = p - r * 14;
        const float* px = xb + r * 56 + c * 2;
        const float2 t01 = *reinterpret_cast<const float2*>(px);
        const float2 t23 = *reinterpret_cast<const float2*>(px + 28);

        float sp0, cp0, sph, cph;
        __sincosf(t01.x, &sp0, &cp0);        // sin p0, cos p0
        __sincosf(t01.y + t1, &sph, &cph);   // sin/cos(p1 + t1)
        const float cp2 = __cosf(t23.x);
        const float cp3 = __cosf(t23.y);

        const float e0 = K1 * cp0 - K2 * sp0 * sph;
        const float e1 = K3 * cp0 * cph;
        const float e2 = cp2;
        const float e3 = K4 * cp2 * cp3;

#pragma unroll
        for (int k = 0; k < 10; ++k) {
            const float4 w4 = *reinterpret_cast<const float4*>(&W[k * 784 + 4 * p]);
            acc[k] += e0 * w4.x + e1 * w4.y + e2 * w4.z + e3 * w4.w;
        }
    };

#pragma unroll
    for (int i = 0; i < 3; ++i) do_patch(lane + 64 * i);
    if (lane < 4) do_patch(192 + lane);      // 196 = 3*64 + 4

    // in-wave butterfly: afterwards EVERY lane holds all 10 full sums
#pragma unroll
    for (int m = 1; m < 64; m <<= 1) {
#pragma unroll
        for (int k = 0; k < 10; ++k) acc[k] += __shfl_xor(acc[k], m, 64);
    }

    // lane-parallel log_softmax over the 10 classes (lanes 0..9 active,
    // reductions within a 16-lane group; lanes >=10 carry neutral values)
    float v = acc[0];
#pragma unroll
    for (int k = 1; k < 10; ++k) v = (lane == k) ? acc[k] : v;
    v += bias[lane < 10 ? lane : 0];

    float m = (lane < 10) ? v : -1e30f;
#pragma unroll
    for (int off = 1; off < 16; off <<= 1) m = fmaxf(m, __shfl_xor(m, off, 16));
    float s = (lane < 10) ? __expf(v - m) : 0.f;
#pragma unroll
    for (int off = 1; off < 16; off <<= 1) s += __shfl_xor(s, off, 16);
    const float lse = m + __logf(s);

    if (lane < 10) out[(size_t)b * 10 + lane] = v - lse;
}

extern "C" void kernel_launch(void* const* d_in, const int* in_sizes, int n_in,
                              void* d_out, int out_size, void* d_ws, size_t ws_size,
                              hipStream_t stream) {
    const float* x     = (const float*)d_in[0];  // [B,28,28]
    const float* theta = (const float*)d_in[1];  // [6]
    const float* W     = (const float*)d_in[2];  // [10,784]
    const float* bias  = (const float*)d_in[3];  // [10]
    float* out = (float*)d_out;                  // [B,10]

    const int B = in_sizes[0] / 784;             // 4096
    const int blocks = (B + 3) / 4;              // 4 samples (waves) per block
    quanv_fused_kernel<<<dim3(blocks), dim3(256), 0, stream>>>(x, theta, W, bias, out, B);
}